// Round 1
// baseline (4682.653 us; speedup 1.0000x reference)
//
#include <hip/hip_runtime.h>
#include <cstdint>

#define TT 300   // timesteps
#define TC 75    // TT/4
#define NBATCH 4

// PSP + refractory IIR step, exact op order of the reference scan.
__device__ __forceinline__ void psp_step(float z, float& gp, float& hp, float& gr, float& hr, float& s_out) {
    hp = 0.90483741803595957f * (hp + gp);      // a_sr = exp(-1/10)
    gp = 0.90483741803595957f * gp + z;
    hr = 0.36787944117144233f * (hr + gr);      // a_rf = exp(-1)
    gr = 0.36787944117144233f * gr;
    float u = 0.27182818284590452f * hp + (-54.365636569180904f) * hr; // c_sr*hp + c_rf*hr
    float s = (u >= 10.0f) ? 1.0f : 0.0f;
    gr += s;
    s_out = s;
}

// Phase B: per-neuron scan over T. Layout [neuron][300].
__global__ void k_scan(const float* __restrict__ z, float* __restrict__ s, int n_neur) {
    int i = blockIdx.x * blockDim.x + threadIdx.x;
    if (i >= n_neur) return;
    const float* zp = z + (size_t)i * TT;
    float* sp = s + (size_t)i * TT;
    float gp = 0.f, hp = 0.f, gr = 0.f, hr = 0.f;
    for (int tc = 0; tc < TC; ++tc) {
        float4 zv = *(const float4*)(zp + tc * 4);
        float4 sv;
        psp_step(zv.x, gp, hp, gr, hr, sv.x);
        psp_step(zv.y, gp, hp, gr, hr, sv.y);
        psp_step(zv.z, gp, hp, gr, hr, sv.z);
        psp_step(zv.w, gp, hp, gr, hr, sv.w);
        *(float4*)(sp + tc * 4) = sv;
    }
}

// Phase A: 4x4 sum-pool * 11.0 over (N,2,128,128,T) -> z (N,2,32,32,T). Thread = (p, tc), tc fastest.
__global__ void k_pool4(const float* __restrict__ x, float* __restrict__ z) {
    int idx = blockIdx.x * 256 + threadIdx.x;
    if (idx >= NBATCH * 2 * 32 * 32 * TC) return;
    int tc = idx % TC;
    int p  = idx / TC;               // (n*2+c)*32*32 + h*32 + w
    int w  = p % 32;
    int h  = (p / 32) % 32;
    int nc = p / (32 * 32);
    const float* base = x + (((size_t)nc * 128 + h * 4) * 128 + w * 4) * TT + tc * 4;
    float ax = 0.f, ay = 0.f, az = 0.f, aw = 0.f;
#pragma unroll
    for (int i = 0; i < 4; ++i)
#pragma unroll
        for (int j = 0; j < 4; ++j) {
            float4 v = *(const float4*)(base + ((size_t)i * 128 + j) * TT);
            ax += v.x; ay += v.y; az += v.z; aw += v.w;
        }
    float4 o; o.x = 11.0f * ax; o.y = 11.0f * ay; o.z = 11.0f * az; o.w = 11.0f * aw;
    *(float4*)(z + (size_t)p * TT + tc * 4) = o;
}

// Phase A: 2x2 sum-pool * 11.0. Output dims (C,H,W); input is (C,2H,2W).
template <int C, int H, int W>
__global__ void k_pool2(const float* __restrict__ s, float* __restrict__ z) {
    int idx = blockIdx.x * 256 + threadIdx.x;
    if (idx >= NBATCH * C * H * W * TC) return;
    int tc = idx % TC;
    int p  = idx / TC;
    int w  = p % W;
    int h  = (p / W) % H;
    int nc = p / (W * H);
    const float* base = s + (((size_t)nc * (2 * H) + h * 2) * (2 * W) + w * 2) * TT + tc * 4;
    float ax = 0.f, ay = 0.f, az = 0.f, aw = 0.f;
#pragma unroll
    for (int i = 0; i < 2; ++i)
#pragma unroll
        for (int j = 0; j < 2; ++j) {
            float4 v = *(const float4*)(base + ((size_t)i * (2 * W) + j) * TT);
            ax += v.x; ay += v.y; az += v.z; aw += v.w;
        }
    float4 o; o.x = 11.0f * ax; o.y = 11.0f * ay; o.z = 11.0f * az; o.w = 11.0f * aw;
    *(float4*)(z + (size_t)p * TT + tc * 4) = o;
}

// Fused conv1 (5x5, pad 2, 2->32) + psp. Thread = one output neuron (n,co,y,x); weights cached in regs.
__global__ void k_conv1_psp(const float* __restrict__ s_in, const float* __restrict__ wgt,
                            float* __restrict__ s_out) {
    constexpr int CIN = 2, COUT = 32, H = 32, W = 32, K = 5, PAD = 2;
    int p = blockIdx.x * 256 + threadIdx.x;
    if (p >= NBATCH * COUT * H * W) return;
    int x = p % W, y = (p / W) % H, co = (p / (W * H)) % COUT, n = p / (W * H * COUT);
    float wr[CIN * K * K];
#pragma unroll
    for (int i = 0; i < CIN * K * K; ++i) wr[i] = wgt[co * CIN * K * K + i];
    const float* sb = s_in + (size_t)n * CIN * H * W * TT;
    float* op = s_out + (size_t)p * TT;
    float gp = 0.f, hp = 0.f, gr = 0.f, hr = 0.f;
    for (int tc = 0; tc < TC; ++tc) {
        float ax = 0.f, ay = 0.f, az = 0.f, aw = 0.f;
#pragma unroll
        for (int ci = 0; ci < CIN; ++ci)
#pragma unroll
            for (int ky = 0; ky < K; ++ky) {
                int yy = y + ky - PAD;
                if (yy < 0 || yy >= H) continue;
#pragma unroll
                for (int kx = 0; kx < K; ++kx) {
                    int xx = x + kx - PAD;
                    if (xx < 0 || xx >= W) continue;
                    float wv = wr[(ci * K + ky) * K + kx];
                    float4 v = *(const float4*)(sb + ((size_t)(ci * H + yy) * W + xx) * TT + tc * 4);
                    ax += wv * v.x; ay += wv * v.y; az += wv * v.z; aw += wv * v.w;
                }
            }
        float4 sv;
        psp_step(ax, gp, hp, gr, hr, sv.x);
        psp_step(ay, gp, hp, gr, hr, sv.y);
        psp_step(az, gp, hp, gr, hr, sv.z);
        psp_step(aw, gp, hp, gr, hr, sv.w);
        *(float4*)(op + tc * 4) = sv;
    }
}

// Phase A split conv (cross-correlation, OIHW weights). Thread = (p, tc), tc fastest -> coalesced.
template <int CIN, int COUT, int H, int W, int K, int PAD>
__global__ void k_conv_a(const float* __restrict__ s_in, const float* __restrict__ wgt,
                         float* __restrict__ z) {
    int idx = blockIdx.x * 256 + threadIdx.x;
    if (idx >= NBATCH * COUT * H * W * TC) return;
    int tc = idx % TC;
    int p  = idx / TC;
    int x = p % W, y = (p / W) % H, co = (p / (W * H)) % COUT, n = p / (W * H * COUT);
    const float* wb = wgt + (size_t)co * CIN * K * K;
    const float* sb = s_in + (size_t)n * CIN * H * W * TT + tc * 4;
    float ax = 0.f, ay = 0.f, az = 0.f, aw = 0.f;
#pragma unroll 4
    for (int ci = 0; ci < CIN; ++ci) {
#pragma unroll
        for (int ky = 0; ky < K; ++ky) {
            int yy = y + ky - PAD;
            if (yy < 0 || yy >= H) continue;
#pragma unroll
            for (int kx = 0; kx < K; ++kx) {
                int xx = x + kx - PAD;
                if (xx < 0 || xx >= W) continue;
                float wv = wb[(ci * K + ky) * K + kx];
                float4 v = *(const float4*)(sb + ((size_t)(ci * H + yy) * W + xx) * TT);
                ax += wv * v.x; ay += wv * v.y; az += wv * v.z; aw += wv * v.w;
            }
        }
    }
    *(float4*)(z + (size_t)p * TT + tc * 4) = make_float4(ax, ay, az, aw);
}

// Phase A FC: z[n][o][t] = sum_f s[n][f][t] * w[o][f]. Thread handles OPER outputs x 4 timesteps.
template <int OUT, int FIN, int OPER>
__global__ void k_fc_a(const float* __restrict__ s, const float* __restrict__ wgt,
                       float* __restrict__ z) {
    constexpr int OG = OUT / OPER;
    int idx = blockIdx.x * 256 + threadIdx.x;
    if (idx >= NBATCH * OG * TC) return;
    int tc = idx % TC;
    int og = (idx / TC) % OG;
    int n  = idx / (TC * OG);
    const float* sb = s + (size_t)n * FIN * TT + tc * 4;
    float acc[OPER][4];
#pragma unroll
    for (int k = 0; k < OPER; ++k) { acc[k][0] = acc[k][1] = acc[k][2] = acc[k][3] = 0.f; }
#pragma unroll 2
    for (int f = 0; f < FIN; f += 4) {
        float4 s0 = *(const float4*)(sb + (size_t)(f + 0) * TT);
        float4 s1 = *(const float4*)(sb + (size_t)(f + 1) * TT);
        float4 s2 = *(const float4*)(sb + (size_t)(f + 2) * TT);
        float4 s3 = *(const float4*)(sb + (size_t)(f + 3) * TT);
#pragma unroll
        for (int k = 0; k < OPER; ++k) {
            float4 wv = *(const float4*)(wgt + (size_t)(og * OPER + k) * FIN + f);
            acc[k][0] += wv.x * s0.x + wv.y * s1.x + wv.z * s2.x + wv.w * s3.x;
            acc[k][1] += wv.x * s0.y + wv.y * s1.y + wv.z * s2.y + wv.w * s3.y;
            acc[k][2] += wv.x * s0.z + wv.y * s1.z + wv.z * s2.z + wv.w * s3.z;
            acc[k][3] += wv.x * s0.w + wv.y * s1.w + wv.z * s2.w + wv.w * s3.w;
        }
    }
#pragma unroll
    for (int k = 0; k < OPER; ++k) {
        float4 o; o.x = acc[k][0]; o.y = acc[k][1]; o.z = acc[k][2]; o.w = acc[k][3];
        *(float4*)(z + (size_t)(n * OUT + og * OPER + k) * TT + tc * 4) = o;
    }
}

extern "C" void kernel_launch(void* const* d_in, const int* in_sizes, int n_in,
                              void* d_out, int out_size, void* d_ws, size_t ws_size,
                              hipStream_t stream) {
    const float* s_in = (const float*)d_in[0]; // (4,2,128,128,300)
    const float* w1   = (const float*)d_in[1]; // (32,2,5,5)
    const float* w2   = (const float*)d_in[2]; // (64,32,3,3)
    const float* w3   = (const float*)d_in[3]; // (64,64,3,3)
    const float* w4a  = (const float*)d_in[4]; // (256,4096)
    const float* w4b  = (const float*)d_in[5]; // (11,256)
    float* out = (float*)d_out;                // (4,11,300)

    // Workspace layout (floats): Z = shared pre-activation region (max z3 = 19,660,800),
    // A/B = ping-pong spike buffers (max 9,830,400 / 39,321,600). Total 275.25 MB.
    float* Z = (float*)d_ws;
    float* A = Z + 19660800;
    float* B = A + 9830400;

    auto g = [](int n) { return (n + 255) / 256; };

    // L0: 4x4 pool + psp  -> s0 in A (4,2,32,32,300)
    k_pool4<<<g(614400), 256, 0, stream>>>(s_in, Z);
    k_scan<<<g(8192), 256, 0, stream>>>(Z, A, 8192);
    // L1: conv 5x5 (2->32) + psp fused -> s1 in B (4,32,32,32,300)
    k_conv1_psp<<<g(131072), 256, 0, stream>>>(A, w1, B);
    // L2: 2x2 pool + psp -> s2 in A (4,32,16,16,300)
    k_pool2<32, 16, 16><<<g(2457600), 256, 0, stream>>>(B, Z);
    k_scan<<<g(32768), 256, 0, stream>>>(Z, A, 32768);
    // L3: conv 3x3 (32->64) + psp -> s3 in B (4,64,16,16,300)
    k_conv_a<32, 64, 16, 16, 3, 1><<<g(4915200), 256, 0, stream>>>(A, w2, Z);
    k_scan<<<g(65536), 256, 0, stream>>>(Z, B, 65536);
    // L4: 2x2 pool + psp -> s4 in A (4,64,8,8,300)
    k_pool2<64, 8, 8><<<g(1228800), 256, 0, stream>>>(B, Z);
    k_scan<<<g(16384), 256, 0, stream>>>(Z, A, 16384);
    // L5: conv 3x3 (64->64) + psp -> s5 in B (4,64,8,8,300)
    k_conv_a<64, 64, 8, 8, 3, 1><<<g(1228800), 256, 0, stream>>>(A, w3, Z);
    k_scan<<<g(16384), 256, 0, stream>>>(Z, B, 16384);
    // L6: fc 4096->256 + psp -> s6 in A (4,256,300)
    k_fc_a<256, 4096, 4><<<g(19200), 256, 0, stream>>>(B, w4a, Z);
    k_scan<<<g(1024), 256, 0, stream>>>(Z, A, 1024);
    // L7: fc 256->11 + psp -> out (4,11,300)
    k_fc_a<11, 256, 1><<<g(3300), 256, 0, stream>>>(A, w4b, Z);
    k_scan<<<1, 64, 0, stream>>>(Z, out, 44);
}

// Round 2
// 1767.636 us; speedup vs baseline: 2.6491x; 2.6491x over previous
//
#include <hip/hip_runtime.h>
#include <cstdint>

#define TT 300   // timesteps
#define TC 75    // TT/4
#define NBATCH 4

// PSP + refractory IIR step, exact op order of the reference scan.
__device__ __forceinline__ void psp_step(float z, float& gp, float& hp, float& gr, float& hr, float& s_out) {
    hp = 0.90483741803595957f * (hp + gp);      // a_sr = exp(-1/10)
    gp = 0.90483741803595957f * gp + z;
    hr = 0.36787944117144233f * (hr + gr);      // a_rf = exp(-1)
    gr = 0.36787944117144233f * gr;
    float u = 0.27182818284590452f * hp + (-54.365636569180904f) * hr; // c_sr*hp + c_rf*hr
    float s = (u >= 10.0f) ? 1.0f : 0.0f;
    gr += s;
    s_out = s;
}

// Phase B: per-neuron scan over T. Layout [neuron][300].
__global__ void k_scan(const float* __restrict__ z, float* __restrict__ s, int n_neur) {
    int i = blockIdx.x * blockDim.x + threadIdx.x;
    if (i >= n_neur) return;
    const float* zp = z + (size_t)i * TT;
    float* sp = s + (size_t)i * TT;
    float gp = 0.f, hp = 0.f, gr = 0.f, hr = 0.f;
    for (int tc = 0; tc < TC; ++tc) {
        float4 zv = *(const float4*)(zp + tc * 4);
        float4 sv;
        psp_step(zv.x, gp, hp, gr, hr, sv.x);
        psp_step(zv.y, gp, hp, gr, hr, sv.y);
        psp_step(zv.z, gp, hp, gr, hr, sv.z);
        psp_step(zv.w, gp, hp, gr, hr, sv.w);
        *(float4*)(sp + tc * 4) = sv;
    }
}

// Phase B with R-way partial-sum reduction first (for f-split FC). stride in floats.
template <int R>
__global__ void k_scan_red(const float* __restrict__ z, float* __restrict__ s, int n_neur, int stride) {
    int i = blockIdx.x * blockDim.x + threadIdx.x;
    if (i >= n_neur) return;
    const float* zp = z + (size_t)i * TT;
    float* sp = s + (size_t)i * TT;
    float gp = 0.f, hp = 0.f, gr = 0.f, hr = 0.f;
    for (int tc = 0; tc < TC; ++tc) {
        float4 zv = *(const float4*)(zp + tc * 4);
#pragma unroll
        for (int r = 1; r < R; ++r) {
            float4 b = *(const float4*)(zp + (size_t)r * stride + tc * 4);
            zv.x += b.x; zv.y += b.y; zv.z += b.z; zv.w += b.w;
        }
        float4 sv;
        psp_step(zv.x, gp, hp, gr, hr, sv.x);
        psp_step(zv.y, gp, hp, gr, hr, sv.y);
        psp_step(zv.z, gp, hp, gr, hr, sv.z);
        psp_step(zv.w, gp, hp, gr, hr, sv.w);
        *(float4*)(sp + tc * 4) = sv;
    }
}

// Repack OIHW weights (COUT, S=CIN*K*K) -> [cg][s][4] so 4 output channels' weights
// for one tap are one float4. COPER fixed at 4.
__global__ void k_pack_w(const float* __restrict__ w, float* __restrict__ wp, int S, int total) {
    int i = blockIdx.x * 256 + threadIdx.x;
    if (i >= total) return;
    int s = i % S;
    int co = i / S;
    wp[((size_t)(co / 4) * S + s) * 4 + (co % 4)] = w[i];
}

// Phase A: 4x4 sum-pool * 11.0 over (N,2,128,128,T) -> z (N,2,32,32,T). Thread = (p, tc), tc fastest.
__global__ void k_pool4(const float* __restrict__ x, float* __restrict__ z) {
    int idx = blockIdx.x * 256 + threadIdx.x;
    if (idx >= NBATCH * 2 * 32 * 32 * TC) return;
    int tc = idx % TC;
    int p  = idx / TC;
    int w  = p % 32;
    int h  = (p / 32) % 32;
    int nc = p / (32 * 32);
    const float* base = x + (((size_t)nc * 128 + h * 4) * 128 + w * 4) * TT + tc * 4;
    float ax = 0.f, ay = 0.f, az = 0.f, aw = 0.f;
#pragma unroll
    for (int i = 0; i < 4; ++i)
#pragma unroll
        for (int j = 0; j < 4; ++j) {
            float4 v = *(const float4*)(base + ((size_t)i * 128 + j) * TT);
            ax += v.x; ay += v.y; az += v.z; aw += v.w;
        }
    float4 o; o.x = 11.0f * ax; o.y = 11.0f * ay; o.z = 11.0f * az; o.w = 11.0f * aw;
    *(float4*)(z + (size_t)p * TT + tc * 4) = o;
}

// Phase A: 2x2 sum-pool * 11.0. Output dims (C,H,W); input is (C,2H,2W).
template <int C, int H, int W>
__global__ void k_pool2(const float* __restrict__ s, float* __restrict__ z) {
    int idx = blockIdx.x * 256 + threadIdx.x;
    if (idx >= NBATCH * C * H * W * TC) return;
    int tc = idx % TC;
    int p  = idx / TC;
    int w  = p % W;
    int h  = (p / W) % H;
    int nc = p / (W * H);
    const float* base = s + (((size_t)nc * (2 * H) + h * 2) * (2 * W) + w * 2) * TT + tc * 4;
    float ax = 0.f, ay = 0.f, az = 0.f, aw = 0.f;
#pragma unroll
    for (int i = 0; i < 2; ++i)
#pragma unroll
        for (int j = 0; j < 2; ++j) {
            float4 v = *(const float4*)(base + ((size_t)i * (2 * W) + j) * TT);
            ax += v.x; ay += v.y; az += v.z; aw += v.w;
        }
    float4 o; o.x = 11.0f * ax; o.y = 11.0f * ay; o.z = 11.0f * az; o.w = 11.0f * aw;
    *(float4*)(z + (size_t)p * TT + tc * 4) = o;
}

// Phase A conv with 4-way output-channel batching. Thread = (n, cg, y, x, tc), tc fastest.
// Weights pre-packed [cg][s][4]. Each input float4 feeds 16 FMAs (4 channels x 4 timesteps).
template <int NB, int CIN, int COUT, int H, int W, int K, int PAD>
__global__ void k_conv_a4(const float* __restrict__ s_in, const float* __restrict__ wp,
                          float* __restrict__ z) {
    constexpr int COG = COUT / 4, S = CIN * K * K;
    int idx = blockIdx.x * 256 + threadIdx.x;
    if (idx >= NB * COG * H * W * TC) return;
    int tc = idx % TC;
    int r  = idx / TC;
    int x = r % W; r /= W;
    int y = r % H; r /= H;
    int cg = r % COG;
    int n  = r / COG;
    const float* sb = s_in + (size_t)n * CIN * H * W * TT + tc * 4;
    const float* wb = wp + (size_t)cg * S * 4;
    float acc[4][4];
#pragma unroll
    for (int k = 0; k < 4; ++k) { acc[k][0] = acc[k][1] = acc[k][2] = acc[k][3] = 0.f; }
#pragma unroll 2
    for (int ci = 0; ci < CIN; ++ci) {
#pragma unroll
        for (int ky = 0; ky < K; ++ky) {
            int yy = y + ky - PAD;
            if (yy < 0 || yy >= H) continue;
#pragma unroll
            for (int kx = 0; kx < K; ++kx) {
                int xx = x + kx - PAD;
                if (xx < 0 || xx >= W) continue;
                float4 v  = *(const float4*)(sb + ((size_t)(ci * H + yy) * W + xx) * TT);
                float4 wv = *(const float4*)(wb + ((ci * K + ky) * K + kx) * 4);
                acc[0][0] += wv.x * v.x; acc[0][1] += wv.x * v.y; acc[0][2] += wv.x * v.z; acc[0][3] += wv.x * v.w;
                acc[1][0] += wv.y * v.x; acc[1][1] += wv.y * v.y; acc[1][2] += wv.y * v.z; acc[1][3] += wv.y * v.w;
                acc[2][0] += wv.z * v.x; acc[2][1] += wv.z * v.y; acc[2][2] += wv.z * v.z; acc[2][3] += wv.z * v.w;
                acc[3][0] += wv.w * v.x; acc[3][1] += wv.w * v.y; acc[3][2] += wv.w * v.z; acc[3][3] += wv.w * v.w;
            }
        }
    }
#pragma unroll
    for (int k = 0; k < 4; ++k) {
        float4 o; o.x = acc[k][0]; o.y = acc[k][1]; o.z = acc[k][2]; o.w = acc[k][3];
        *(float4*)(z + ((size_t)(n * COUT + cg * 4 + k) * H * W + y * W + x) * TT + tc * 4) = o;
    }
}

// Phase A FC with f-split: partial z[sp][n][o][t] = sum_{f in chunk sp} s[n][f][t]*w[o][f].
template <int OUT, int FIN, int OPER, int FSPLIT>
__global__ void k_fc_a(const float* __restrict__ s, const float* __restrict__ wgt,
                       float* __restrict__ z) {
    constexpr int OG = OUT / OPER, FCH = FIN / FSPLIT;
    int idx = blockIdx.x * 256 + threadIdx.x;
    if (idx >= NBATCH * OG * TC * FSPLIT) return;
    int tc = idx % TC;
    int og = (idx / TC) % OG;
    int n  = (idx / (TC * OG)) % NBATCH;
    int sp = idx / (TC * OG * NBATCH);
    const float* sb = s + (size_t)n * FIN * TT + (size_t)sp * FCH * TT + tc * 4;
    const float* wb = wgt + (size_t)sp * FCH;
    float acc[OPER][4];
#pragma unroll
    for (int k = 0; k < OPER; ++k) { acc[k][0] = acc[k][1] = acc[k][2] = acc[k][3] = 0.f; }
#pragma unroll 2
    for (int f = 0; f < FCH; f += 4) {
        float4 s0 = *(const float4*)(sb + (size_t)(f + 0) * TT);
        float4 s1 = *(const float4*)(sb + (size_t)(f + 1) * TT);
        float4 s2 = *(const float4*)(sb + (size_t)(f + 2) * TT);
        float4 s3 = *(const float4*)(sb + (size_t)(f + 3) * TT);
#pragma unroll
        for (int k = 0; k < OPER; ++k) {
            float4 wv = *(const float4*)(wb + (size_t)(og * OPER + k) * FIN + f);
            acc[k][0] += wv.x * s0.x + wv.y * s1.x + wv.z * s2.x + wv.w * s3.x;
            acc[k][1] += wv.x * s0.y + wv.y * s1.y + wv.z * s2.y + wv.w * s3.y;
            acc[k][2] += wv.x * s0.z + wv.y * s1.z + wv.z * s2.z + wv.w * s3.z;
            acc[k][3] += wv.x * s0.w + wv.y * s1.w + wv.z * s2.w + wv.w * s3.w;
        }
    }
#pragma unroll
    for (int k = 0; k < OPER; ++k) {
        float4 o; o.x = acc[k][0]; o.y = acc[k][1]; o.z = acc[k][2]; o.w = acc[k][3];
        *(float4*)(z + ((size_t)sp * NBATCH * OUT + (size_t)n * OUT + og * OPER + k) * TT + tc * 4) = o;
    }
}

extern "C" void kernel_launch(void* const* d_in, const int* in_sizes, int n_in,
                              void* d_out, int out_size, void* d_ws, size_t ws_size,
                              hipStream_t stream) {
    const float* s_in = (const float*)d_in[0]; // (4,2,128,128,300)
    const float* w1   = (const float*)d_in[1]; // (32,2,5,5)
    const float* w2   = (const float*)d_in[2]; // (64,32,3,3)
    const float* w3   = (const float*)d_in[3]; // (64,64,3,3)
    const float* w4a  = (const float*)d_in[4]; // (256,4096)
    const float* w4b  = (const float*)d_in[5]; // (11,256)
    float* out = (float*)d_out;                // (4,11,300)

    // Workspace (floats): Z 9,830,400 | A 9,830,400 | B 39,321,600 | packed weights 57,344.
    // Total 236.4 MB (< proven-available 275 MB). Convs chunked over batch so z fits Z.
    float* Z = (float*)d_ws;
    float* A = Z + 9830400;
    float* B = A + 9830400;
    float* WP = B + 39321600;
    float* w1p = WP;                 // 8  x 50  x 4 = 1600
    float* w2p = WP + 1600;          // 16 x 288 x 4 = 18432
    float* w3p = WP + 1600 + 18432;  // 16 x 576 x 4 = 36864

    auto g = [](int n) { return (n + 255) / 256; };

    k_pack_w<<<g(1600),  256, 0, stream>>>(w1, w1p, 50, 1600);
    k_pack_w<<<g(18432), 256, 0, stream>>>(w2, w2p, 288, 18432);
    k_pack_w<<<g(36864), 256, 0, stream>>>(w3, w3p, 576, 36864);

    // L0: 4x4 pool + psp  -> s0 in A (4,2,32,32,300)
    k_pool4<<<g(614400), 256, 0, stream>>>(s_in, Z);
    k_scan<<<g(8192), 256, 0, stream>>>(Z, A, 8192);

    // L1: conv 5x5 (2->32) + psp -> s1 in B (4,32,32,32,300); 4 batch chunks
    for (int c = 0; c < 4; ++c) {
        k_conv_a4<1, 2, 32, 32, 32, 5, 2><<<g(614400), 256, 0, stream>>>(A + (size_t)c * 614400, w1p, Z);
        k_scan<<<g(32768), 256, 0, stream>>>(Z, B + (size_t)c * 9830400, 32768);
    }

    // L2: 2x2 pool + psp -> s2 in A (4,32,16,16,300)
    k_pool2<32, 16, 16><<<g(2457600), 256, 0, stream>>>(B, Z);
    k_scan<<<g(32768), 256, 0, stream>>>(Z, A, 32768);

    // L3: conv 3x3 (32->64) + psp -> s3 in B (4,64,16,16,300); 2 batch chunks
    for (int c = 0; c < 2; ++c) {
        k_conv_a4<2, 32, 64, 16, 16, 3, 1><<<g(614400), 256, 0, stream>>>(A + (size_t)c * 4915200, w2p, Z);
        k_scan<<<g(32768), 256, 0, stream>>>(Z, B + (size_t)c * 9830400, 32768);
    }

    // L4: 2x2 pool + psp -> s4 in A (4,64,8,8,300)
    k_pool2<64, 8, 8><<<g(1228800), 256, 0, stream>>>(B, Z);
    k_scan<<<g(16384), 256, 0, stream>>>(Z, A, 16384);

    // L5: conv 3x3 (64->64) + psp -> s5 in B (4,64,8,8,300)
    k_conv_a4<4, 64, 64, 8, 8, 3, 1><<<g(307200), 256, 0, stream>>>(A, w3p, Z);
    k_scan<<<g(16384), 256, 0, stream>>>(Z, B, 16384);

    // L6: fc 4096->256 + psp -> s6 in A (4,256,300); 8-way f-split partials then reduce+scan
    k_fc_a<256, 4096, 4, 8><<<g(153600), 256, 0, stream>>>(B, w4a, Z);
    k_scan_red<8><<<g(1024), 256, 0, stream>>>(Z, A, 1024, 307200);

    // L7: fc 256->11 + psp -> out (4,11,300)
    k_fc_a<11, 256, 1, 1><<<g(3300), 256, 0, stream>>>(A, w4b, Z);
    k_scan_red<1><<<1, 64, 0, stream>>>(Z, out, 44, 0);
}

// Round 3
// 1537.305 us; speedup vs baseline: 3.0460x; 1.1498x over previous
//
#include <hip/hip_runtime.h>
#include <cstdint>

#define TT 300   // timesteps
#define TC 75    // TT/4
#define NBATCH 4

// PSP + refractory IIR step, exact op order of the reference scan.
__device__ __forceinline__ void psp_step(float z, float& gp, float& hp, float& gr, float& hr, float& s_out) {
    hp = 0.90483741803595957f * (hp + gp);      // a_sr = exp(-1/10)
    gp = 0.90483741803595957f * gp + z;
    hr = 0.36787944117144233f * (hr + gr);      // a_rf = exp(-1)
    gr = 0.36787944117144233f * gr;
    float u = 0.27182818284590452f * hp + (-54.365636569180904f) * hr; // c_sr*hp + c_rf*hr
    float s = (u >= 10.0f) ? 1.0f : 0.0f;
    gr += s;
    s_out = s;
}

// Plain per-neuron scan (layer 0 only). Layout [neuron][300].
__global__ void k_scan(const float* __restrict__ z, float* __restrict__ s, int n_neur) {
    int i = blockIdx.x * blockDim.x + threadIdx.x;
    if (i >= n_neur) return;
    const float* zp = z + (size_t)i * TT;
    float* sp = s + (size_t)i * TT;
    float gp = 0.f, hp = 0.f, gr = 0.f, hr = 0.f;
    for (int tc = 0; tc < TC; ++tc) {
        float4 zv = *(const float4*)(zp + tc * 4);
        float4 sv;
        psp_step(zv.x, gp, hp, gr, hr, sv.x);
        psp_step(zv.y, gp, hp, gr, hr, sv.y);
        psp_step(zv.z, gp, hp, gr, hr, sv.z);
        psp_step(zv.w, gp, hp, gr, hr, sv.w);
        *(float4*)(sp + tc * 4) = sv;
    }
}

// Scan with R-way partial-sum reduction first. stride in floats between partials.
template <int R>
__global__ void k_scan_red(const float* __restrict__ z, float* __restrict__ s, int n_neur, int stride) {
    int i = blockIdx.x * blockDim.x + threadIdx.x;
    if (i >= n_neur) return;
    const float* zp = z + (size_t)i * TT;
    float* sp = s + (size_t)i * TT;
    float gp = 0.f, hp = 0.f, gr = 0.f, hr = 0.f;
    for (int tc = 0; tc < TC; ++tc) {
        float4 zv = *(const float4*)(zp + tc * 4);
#pragma unroll
        for (int r = 1; r < R; ++r) {
            float4 b = *(const float4*)(zp + (size_t)r * stride + tc * 4);
            zv.x += b.x; zv.y += b.y; zv.z += b.z; zv.w += b.w;
        }
        float4 sv;
        psp_step(zv.x, gp, hp, gr, hr, sv.x);
        psp_step(zv.y, gp, hp, gr, hr, sv.y);
        psp_step(zv.z, gp, hp, gr, hr, sv.z);
        psp_step(zv.w, gp, hp, gr, hr, sv.w);
        *(float4*)(sp + tc * 4) = sv;
    }
}

// Fused: psp-scan of conv layer (R partials) -> 2x2 sum-pool*11 -> psp-scan of pooled layer.
// Thread owns a 2x2 quad of conv neurons (4 IIR states) + the pooled neuron (1 IIR state).
// z layout: [sp][n][C][H][W][T] with H=2*H2, W=2*W2; writes s [n][C][H2][W2][T].
template <int R, int C, int H2, int W2>
__global__ void k_scan_pool_scan(const float* __restrict__ z, float* __restrict__ s, int pstride) {
    constexpr int H = 2 * H2, W = 2 * W2;
    int i = blockIdx.x * 256 + threadIdx.x;
    if (i >= NBATCH * C * H2 * W2) return;
    int x2 = i % W2;
    int y2 = (i / W2) % H2;
    int c  = (i / (W2 * H2)) % C;
    int n  = i / (W2 * H2 * C);
    const float* zb = z + (((size_t)(n * C + c) * H + 2 * y2) * W + 2 * x2) * TT;
    float gp[4] = {0,0,0,0}, hp[4] = {0,0,0,0}, gr[4] = {0,0,0,0}, hr[4] = {0,0,0,0};
    float Gp = 0.f, Hp = 0.f, Gr = 0.f, Hr = 0.f;
    float* so = s + (size_t)i * TT;
    for (int tc = 0; tc < TC; ++tc) {
        float zq[4][4];
#pragma unroll
        for (int q = 0; q < 4; ++q) {
            const float* p = zb + ((size_t)(q >> 1) * W + (q & 1)) * TT + tc * 4;
            float4 a = *(const float4*)p;
#pragma unroll
            for (int r = 1; r < R; ++r) {
                float4 b = *(const float4*)(p + (size_t)r * pstride);
                a.x += b.x; a.y += b.y; a.z += b.z; a.w += b.w;
            }
            zq[q][0] = a.x; zq[q][1] = a.y; zq[q][2] = a.z; zq[q][3] = a.w;
        }
        float out[4];
#pragma unroll
        for (int tt = 0; tt < 4; ++tt) {
            float pool = 0.f;
#pragma unroll
            for (int q = 0; q < 4; ++q) {
                float sq;
                psp_step(zq[q][tt], gp[q], hp[q], gr[q], hr[q], sq);
                pool += sq;
            }
            psp_step(11.0f * pool, Gp, Hp, Gr, Hr, out[tt]);
        }
        float4 ov; ov.x = out[0]; ov.y = out[1]; ov.z = out[2]; ov.w = out[3];
        *(float4*)(so + tc * 4) = ov;
    }
}

// Transpose-pack OIHW weights (COUT, S) -> [s][COUT] so one tap's weights are contiguous.
__global__ void k_pack_w(const float* __restrict__ w, float* __restrict__ wp, int S, int CO, int total) {
    int i = blockIdx.x * 256 + threadIdx.x;
    if (i >= total) return;
    int co = i % CO, s = i / CO;
    wp[i] = w[co * S + s];
}

// 4x4 sum-pool * 11.0 over (N,2,128,128,T) -> z (N,2,32,32,T). Thread = (p, tc), tc fastest.
__global__ void k_pool4(const float* __restrict__ x, float* __restrict__ z) {
    int idx = blockIdx.x * 256 + threadIdx.x;
    if (idx >= NBATCH * 2 * 32 * 32 * TC) return;
    int tc = idx % TC;
    int p  = idx / TC;
    int w  = p % 32;
    int h  = (p / 32) % 32;
    int nc = p / (32 * 32);
    const float* base = x + (((size_t)nc * 128 + h * 4) * 128 + w * 4) * TT + tc * 4;
    float ax = 0.f, ay = 0.f, az = 0.f, aw = 0.f;
#pragma unroll
    for (int i = 0; i < 4; ++i)
#pragma unroll
        for (int j = 0; j < 4; ++j) {
            float4 v = *(const float4*)(base + ((size_t)i * 128 + j) * TT);
            ax += v.x; ay += v.y; az += v.z; aw += v.w;
        }
    float4 o; o.x = 11.0f * ax; o.y = 11.0f * ay; o.z = 11.0f * az; o.w = 11.0f * aw;
    *(float4*)(z + (size_t)p * TT + tc * 4) = o;
}

// LDS-weight conv. Thread = (sp, cb, n, y, x, tc): 16 output channels x 4 timesteps in regs.
// Per tap: 1 input float4 (coalesced) + 4 wave-uniform ds_read_b128 + 64 FMAs.
// Grid must be exact (total threads % 256 == 0); sp is block-uniform by construction.
// z out: [sp][n][COUT][H][W][T].
template <int SPLIT, int CIN, int COUT, int H, int W, int K, int PAD>
__global__ void __launch_bounds__(256) k_conv_lds(const float* __restrict__ s_in,
                                                  const float* __restrict__ wp,
                                                  float* __restrict__ z) {
    constexpr int CBN = COUT / 16;
    constexpr int CIN_SP = CIN / SPLIT;
    constexpr int S_SP = CIN_SP * K * K;
    __shared__ float wlds[S_SP * COUT];
    int sp = (int)(((size_t)blockIdx.x * 256) / (CBN * NBATCH * H * W * TC));
    {
        const float4* src = (const float4*)(wp + (size_t)sp * S_SP * COUT);
        float4* dst = (float4*)wlds;
        for (int i = threadIdx.x; i < S_SP * COUT / 4; i += 256) dst[i] = src[i];
    }
    __syncthreads();
    int t = blockIdx.x * 256 + threadIdx.x;
    int tc = t % TC; t /= TC;
    int x  = t % W;  t /= W;
    int y  = t % H;  t /= H;
    int n  = t % NBATCH; t /= NBATCH;
    int cb = t % CBN;
    const float* sb = s_in + ((size_t)n * CIN + sp * CIN_SP) * H * W * TT + tc * 4;
    float acc[4][4][4]; // [cg][c][t]
#pragma unroll
    for (int a = 0; a < 4; ++a)
#pragma unroll
        for (int b = 0; b < 4; ++b)
#pragma unroll
            for (int d = 0; d < 4; ++d) acc[a][b][d] = 0.f;
#pragma unroll 1
    for (int cl = 0; cl < CIN_SP; ++cl) {
#pragma unroll
        for (int ky = 0; ky < K; ++ky) {
            int yy = y + ky - PAD;
            if (yy < 0 || yy >= H) continue;
#pragma unroll
            for (int kx = 0; kx < K; ++kx) {
                int xx = x + kx - PAD;
                if (xx < 0 || xx >= W) continue;
                float4 v = *(const float4*)(sb + ((size_t)(cl * H + yy) * W + xx) * TT);
                float va[4] = {v.x, v.y, v.z, v.w};
                const float* wrow = &wlds[((cl * K + ky) * K + kx) * COUT + cb * 16];
#pragma unroll
                for (int cg = 0; cg < 4; ++cg) {
                    float4 wv = *(const float4*)(wrow + cg * 4);
                    float wa[4] = {wv.x, wv.y, wv.z, wv.w};
#pragma unroll
                    for (int c = 0; c < 4; ++c)
#pragma unroll
                        for (int tt = 0; tt < 4; ++tt)
                            acc[cg][c][tt] += wa[c] * va[tt];
                }
            }
        }
    }
    float* zb = z + (((size_t)(sp * NBATCH + n) * COUT + cb * 16) * H * W + (size_t)y * W + x) * TT + tc * 4;
#pragma unroll
    for (int cg = 0; cg < 4; ++cg)
#pragma unroll
        for (int c = 0; c < 4; ++c) {
            float4 o; o.x = acc[cg][c][0]; o.y = acc[cg][c][1]; o.z = acc[cg][c][2]; o.w = acc[cg][c][3];
            *(float4*)(zb + (size_t)(cg * 4 + c) * H * W * TT) = o;
        }
}

// FC with f-split: partial z[sp][n][o][t] = sum_{f in chunk sp} s[n][f][t]*w[o][f].
template <int OUT, int FIN, int OPER, int FSPLIT>
__global__ void k_fc_a(const float* __restrict__ s, const float* __restrict__ wgt,
                       float* __restrict__ z) {
    constexpr int OG = OUT / OPER, FCH = FIN / FSPLIT;
    int idx = blockIdx.x * 256 + threadIdx.x;
    if (idx >= NBATCH * OG * TC * FSPLIT) return;
    int tc = idx % TC;
    int og = (idx / TC) % OG;
    int n  = (idx / (TC * OG)) % NBATCH;
    int sp = idx / (TC * OG * NBATCH);
    const float* sb = s + (size_t)n * FIN * TT + (size_t)sp * FCH * TT + tc * 4;
    const float* wb = wgt + (size_t)sp * FCH;
    float acc[OPER][4];
#pragma unroll
    for (int k = 0; k < OPER; ++k) { acc[k][0] = acc[k][1] = acc[k][2] = acc[k][3] = 0.f; }
#pragma unroll 2
    for (int f = 0; f < FCH; f += 4) {
        float4 s0 = *(const float4*)(sb + (size_t)(f + 0) * TT);
        float4 s1 = *(const float4*)(sb + (size_t)(f + 1) * TT);
        float4 s2 = *(const float4*)(sb + (size_t)(f + 2) * TT);
        float4 s3 = *(const float4*)(sb + (size_t)(f + 3) * TT);
#pragma unroll
        for (int k = 0; k < OPER; ++k) {
            float4 wv = *(const float4*)(wb + (size_t)(og * OPER + k) * FIN + f);
            acc[k][0] += wv.x * s0.x + wv.y * s1.x + wv.z * s2.x + wv.w * s3.x;
            acc[k][1] += wv.x * s0.y + wv.y * s1.y + wv.z * s2.y + wv.w * s3.y;
            acc[k][2] += wv.x * s0.z + wv.y * s1.z + wv.z * s2.z + wv.w * s3.z;
            acc[k][3] += wv.x * s0.w + wv.y * s1.w + wv.z * s2.w + wv.w * s3.w;
        }
    }
#pragma unroll
    for (int k = 0; k < OPER; ++k) {
        float4 o; o.x = acc[k][0]; o.y = acc[k][1]; o.z = acc[k][2]; o.w = acc[k][3];
        *(float4*)(z + ((size_t)sp * NBATCH * OUT + (size_t)n * OUT + og * OPER + k) * TT + tc * 4) = o;
    }
}

extern "C" void kernel_launch(void* const* d_in, const int* in_sizes, int n_in,
                              void* d_out, int out_size, void* d_ws, size_t ws_size,
                              hipStream_t stream) {
    const float* s_in = (const float*)d_in[0]; // (4,2,128,128,300)
    const float* w1   = (const float*)d_in[1]; // (32,2,5,5)
    const float* w2   = (const float*)d_in[2]; // (64,32,3,3)
    const float* w3   = (const float*)d_in[3]; // (64,64,3,3)
    const float* w4a  = (const float*)d_in[4]; // (256,4096)
    const float* w4b  = (const float*)d_in[5]; // (11,256)
    float* out = (float*)d_out;                // (4,11,300)

    // Workspace (floats): Z 39,321,600 (pre-activations/partials) | Sb 9,830,400 (spikes,
    // buffers time-multiplexed: s0/s2/s4/s5/s6 all live at offset 0, lifetimes disjoint)
    // | packed weights 56,896. Total ~196.8 MB.
    float* Z  = (float*)d_ws;
    float* Sb = Z + 39321600;
    float* WP = Sb + 9830400;
    float* w1p = WP;           // 50*32   = 1600
    float* w2p = WP + 1600;    // 288*64  = 18432
    float* w3p = WP + 20032;   // 576*64  = 36864

    auto g = [](int n) { return (n + 255) / 256; };

    k_pack_w<<<g(1600),  256, 0, stream>>>(w1, w1p, 50, 32, 1600);
    k_pack_w<<<g(18432), 256, 0, stream>>>(w2, w2p, 288, 64, 18432);
    k_pack_w<<<g(36864), 256, 0, stream>>>(w3, w3p, 576, 64, 36864);

    // L0: 4x4 pool + psp -> s0 (4,2,32,32,300) @ Sb
    k_pool4<<<g(614400), 256, 0, stream>>>(s_in, Z);
    k_scan<<<g(8192), 256, 0, stream>>>(Z, Sb, 8192);

    // L1 conv 5x5 (2->32, 32x32): z1 (39.3M) @ Z. 614400 threads = 2400 blocks exact.
    k_conv_lds<1, 2, 32, 32, 32, 5, 2><<<2400, 256, 0, stream>>>(Sb, w1p, Z);
    // L1 psp + 2x2 pool + L2 psp -> s2 (4,32,16,16,300) @ Sb
    k_scan_pool_scan<1, 32, 16, 16><<<g(32768), 256, 0, stream>>>(Z, Sb, 0);

    // L3 conv 3x3 (32->64, 16x16), ci-split 2: z3 (2 x 19.66M) @ Z. 2400 blocks exact.
    k_conv_lds<2, 32, 64, 16, 16, 3, 1><<<2400, 256, 0, stream>>>(Sb, w2p, Z);
    // L3 psp + 2x2 pool + L4 psp -> s4 (4,64,8,8,300) @ Sb
    k_scan_pool_scan<2, 64, 8, 8><<<g(16384), 256, 0, stream>>>(Z, Sb, 19660800);

    // L5 conv 3x3 (64->64, 8x8), ci-split 4: z5 (4 x 4.92M) @ Z. 1200 blocks exact.
    k_conv_lds<4, 64, 64, 8, 8, 3, 1><<<1200, 256, 0, stream>>>(Sb, w3p, Z);
    k_scan_red<4><<<g(16384), 256, 0, stream>>>(Z, Sb, 16384, 4915200); // s5 @ Sb

    // L6: fc 4096->256, 16-way f-split, 8 outputs/thread: z6 (16 x 307200) @ Z. 600 blocks.
    k_fc_a<256, 4096, 8, 16><<<600, 256, 0, stream>>>(Sb, w4a, Z);
    k_scan_red<16><<<g(1024), 256, 0, stream>>>(Z, Sb, 1024, 307200);   // s6 @ Sb

    // L7: fc 256->11 + psp -> out
    k_fc_a<11, 256, 1, 1><<<g(3300), 256, 0, stream>>>(Sb, w4b, Z);
    k_scan_red<1><<<1, 64, 0, stream>>>(Z, out, 44, 0);
}

// Round 4
// 1104.897 us; speedup vs baseline: 4.2381x; 1.3914x over previous
//
#include <hip/hip_runtime.h>
#include <cstdint>

#define TT 300   // timesteps
#define TC 75    // TT/4
#define NBATCH 4

// PSP + refractory IIR step, exact op order of the reference scan.
__device__ __forceinline__ void psp_step(float z, float& gp, float& hp, float& gr, float& hr, float& s_out) {
    hp = 0.90483741803595957f * (hp + gp);      // a_sr = exp(-1/10)
    gp = 0.90483741803595957f * gp + z;
    hr = 0.36787944117144233f * (hr + gr);      // a_rf = exp(-1)
    gr = 0.36787944117144233f * gr;
    float u = 0.27182818284590452f * hp + (-54.365636569180904f) * hr; // c_sr*hp + c_rf*hr
    float s = (u >= 10.0f) ? 1.0f : 0.0f;
    gr += s;
    s_out = s;
}

// Coalesced R-way partial reduce: zr[p][t] = sum_r z[r*pstride + p*TT + t].
// Thread = (p, tc) tc-fastest; all loads/stores fully coalesced float4.
template <int R>
__global__ void k_reduce(const float* __restrict__ z, float* __restrict__ zr,
                         int total4, int pstride) {
    int i = blockIdx.x * 256 + threadIdx.x;
    if (i >= total4) return;
    size_t pos = (size_t)i * 4;
    float4 a = *(const float4*)(z + pos);
#pragma unroll
    for (int r = 1; r < R; ++r) {
        float4 b = *(const float4*)(z + (size_t)r * pstride + pos);
        a.x += b.x; a.y += b.y; a.z += b.z; a.w += b.w;
    }
    *(float4*)(zr + pos) = a;
}

// Per-neuron scan over T, 64-thread blocks, 12-step chunks (3 independent float4
// loads issued up front per chunk to hide L2/L3 latency behind the IIR chain).
__global__ void k_scan(const float* __restrict__ z, float* __restrict__ s, int n_neur) {
    int i = blockIdx.x * 64 + threadIdx.x;
    if (i >= n_neur) return;
    const float* zp = z + (size_t)i * TT;
    float* sp = s + (size_t)i * TT;
    float gp = 0.f, hp = 0.f, gr = 0.f, hr = 0.f;
#pragma unroll 1
    for (int c = 0; c < 25; ++c) {
        const float* p = zp + c * 12;
        float4 v0 = *(const float4*)(p);
        float4 v1 = *(const float4*)(p + 4);
        float4 v2 = *(const float4*)(p + 8);
        float4 o0, o1, o2;
        psp_step(v0.x, gp, hp, gr, hr, o0.x);
        psp_step(v0.y, gp, hp, gr, hr, o0.y);
        psp_step(v0.z, gp, hp, gr, hr, o0.z);
        psp_step(v0.w, gp, hp, gr, hr, o0.w);
        psp_step(v1.x, gp, hp, gr, hr, o1.x);
        psp_step(v1.y, gp, hp, gr, hr, o1.y);
        psp_step(v1.z, gp, hp, gr, hr, o1.z);
        psp_step(v1.w, gp, hp, gr, hr, o1.w);
        psp_step(v2.x, gp, hp, gr, hr, o2.x);
        psp_step(v2.y, gp, hp, gr, hr, o2.y);
        psp_step(v2.z, gp, hp, gr, hr, o2.z);
        psp_step(v2.w, gp, hp, gr, hr, o2.w);
        float* q = sp + c * 12;
        *(float4*)(q) = o0;
        *(float4*)(q + 4) = o1;
        *(float4*)(q + 8) = o2;
    }
}

// Fused: psp-scan of conv layer (R partials) -> 2x2 sum-pool*11 -> psp-scan of pooled layer.
// Thread owns a 2x2 quad of conv neurons (4 IIR states) + the pooled neuron (1 IIR state).
// z layout: [sp][n][C][H][W][T] with H=2*H2, W=2*W2; writes s [n][C][H2][W2][T].
template <int R, int C, int H2, int W2>
__global__ void k_scan_pool_scan(const float* __restrict__ z, float* __restrict__ s, int pstride) {
    constexpr int H = 2 * H2, W = 2 * W2;
    int i = blockIdx.x * 256 + threadIdx.x;
    if (i >= NBATCH * C * H2 * W2) return;
    int x2 = i % W2;
    int y2 = (i / W2) % H2;
    int c  = (i / (W2 * H2)) % C;
    int n  = i / (W2 * H2 * C);
    const float* zb = z + (((size_t)(n * C + c) * H + 2 * y2) * W + 2 * x2) * TT;
    float gp[4] = {0,0,0,0}, hp[4] = {0,0,0,0}, gr[4] = {0,0,0,0}, hr[4] = {0,0,0,0};
    float Gp = 0.f, Hp = 0.f, Gr = 0.f, Hr = 0.f;
    float* so = s + (size_t)i * TT;
    for (int tc = 0; tc < TC; ++tc) {
        float zq[4][4];
#pragma unroll
        for (int q = 0; q < 4; ++q) {
            const float* p = zb + ((size_t)(q >> 1) * W + (q & 1)) * TT + tc * 4;
            float4 a = *(const float4*)p;
#pragma unroll
            for (int r = 1; r < R; ++r) {
                float4 b = *(const float4*)(p + (size_t)r * pstride);
                a.x += b.x; a.y += b.y; a.z += b.z; a.w += b.w;
            }
            zq[q][0] = a.x; zq[q][1] = a.y; zq[q][2] = a.z; zq[q][3] = a.w;
        }
        float out[4];
#pragma unroll
        for (int tt = 0; tt < 4; ++tt) {
            float pool = 0.f;
#pragma unroll
            for (int q = 0; q < 4; ++q) {
                float sq;
                psp_step(zq[q][tt], gp[q], hp[q], gr[q], hr[q], sq);
                pool += sq;
            }
            psp_step(11.0f * pool, Gp, Hp, Gr, Hr, out[tt]);
        }
        float4 ov; ov.x = out[0]; ov.y = out[1]; ov.z = out[2]; ov.w = out[3];
        *(float4*)(so + tc * 4) = ov;
    }
}

// Transpose-pack OIHW weights (COUT, S) -> [s][COUT] so one tap's weights are contiguous.
__global__ void k_pack_w(const float* __restrict__ w, float* __restrict__ wp, int S, int CO, int total) {
    int i = blockIdx.x * 256 + threadIdx.x;
    if (i >= total) return;
    int co = i % CO, s = i / CO;
    wp[i] = w[co * S + s];
}

// 4x4 sum-pool * 11.0 over (N,2,128,128,T) -> z (N,2,32,32,T). Thread = (p, tc), tc fastest.
__global__ void k_pool4(const float* __restrict__ x, float* __restrict__ z) {
    int idx = blockIdx.x * 256 + threadIdx.x;
    if (idx >= NBATCH * 2 * 32 * 32 * TC) return;
    int tc = idx % TC;
    int p  = idx / TC;
    int w  = p % 32;
    int h  = (p / 32) % 32;
    int nc = p / (32 * 32);
    const float* base = x + (((size_t)nc * 128 + h * 4) * 128 + w * 4) * TT + tc * 4;
    float ax = 0.f, ay = 0.f, az = 0.f, aw = 0.f;
#pragma unroll
    for (int i = 0; i < 4; ++i)
#pragma unroll
        for (int j = 0; j < 4; ++j) {
            float4 v = *(const float4*)(base + ((size_t)i * 128 + j) * TT);
            ax += v.x; ay += v.y; az += v.z; aw += v.w;
        }
    float4 o; o.x = 11.0f * ax; o.y = 11.0f * ay; o.z = 11.0f * az; o.w = 11.0f * aw;
    *(float4*)(z + (size_t)p * TT + tc * 4) = o;
}

// LDS-weight conv. Thread = (sp, cb, n, y, x, tc): 16 output channels x 4 timesteps in regs.
// Per tap: 1 input float4 (coalesced) + 4 wave-uniform ds_read_b128 + 64 FMAs.
// Grid must be exact (total threads % 256 == 0); sp is block-uniform by construction.
// z out: [sp][n][COUT][H][W][T].
template <int SPLIT, int CIN, int COUT, int H, int W, int K, int PAD>
__global__ void __launch_bounds__(256) k_conv_lds(const float* __restrict__ s_in,
                                                  const float* __restrict__ wp,
                                                  float* __restrict__ z) {
    constexpr int CBN = COUT / 16;
    constexpr int CIN_SP = CIN / SPLIT;
    constexpr int S_SP = CIN_SP * K * K;
    __shared__ float wlds[S_SP * COUT];
    int sp = (int)(((size_t)blockIdx.x * 256) / (CBN * NBATCH * H * W * TC));
    {
        const float4* src = (const float4*)(wp + (size_t)sp * S_SP * COUT);
        float4* dst = (float4*)wlds;
        for (int i = threadIdx.x; i < S_SP * COUT / 4; i += 256) dst[i] = src[i];
    }
    __syncthreads();
    int t = blockIdx.x * 256 + threadIdx.x;
    int tc = t % TC; t /= TC;
    int x  = t % W;  t /= W;
    int y  = t % H;  t /= H;
    int n  = t % NBATCH; t /= NBATCH;
    int cb = t % CBN;
    const float* sb = s_in + ((size_t)n * CIN + sp * CIN_SP) * H * W * TT + tc * 4;
    float acc[4][4][4]; // [cg][c][t]
#pragma unroll
    for (int a = 0; a < 4; ++a)
#pragma unroll
        for (int b = 0; b < 4; ++b)
#pragma unroll
            for (int d = 0; d < 4; ++d) acc[a][b][d] = 0.f;
#pragma unroll 1
    for (int cl = 0; cl < CIN_SP; ++cl) {
#pragma unroll
        for (int ky = 0; ky < K; ++ky) {
            int yy = y + ky - PAD;
            if (yy < 0 || yy >= H) continue;
#pragma unroll
            for (int kx = 0; kx < K; ++kx) {
                int xx = x + kx - PAD;
                if (xx < 0 || xx >= W) continue;
                float4 v = *(const float4*)(sb + ((size_t)(cl * H + yy) * W + xx) * TT);
                float va[4] = {v.x, v.y, v.z, v.w};
                const float* wrow = &wlds[((cl * K + ky) * K + kx) * COUT + cb * 16];
#pragma unroll
                for (int cg = 0; cg < 4; ++cg) {
                    float4 wv = *(const float4*)(wrow + cg * 4);
                    float wa[4] = {wv.x, wv.y, wv.z, wv.w};
#pragma unroll
                    for (int c = 0; c < 4; ++c)
#pragma unroll
                        for (int tt = 0; tt < 4; ++tt)
                            acc[cg][c][tt] += wa[c] * va[tt];
                }
            }
        }
    }
    float* zb = z + (((size_t)(sp * NBATCH + n) * COUT + cb * 16) * H * W + (size_t)y * W + x) * TT + tc * 4;
#pragma unroll
    for (int cg = 0; cg < 4; ++cg)
#pragma unroll
        for (int c = 0; c < 4; ++c) {
            float4 o; o.x = acc[cg][c][0]; o.y = acc[cg][c][1]; o.z = acc[cg][c][2]; o.w = acc[cg][c][3];
            *(float4*)(zb + (size_t)(cg * 4 + c) * H * W * TT) = o;
        }
}

// FC with f-split: partial z[sp][n][o][t] = sum_{f in chunk sp} s[n][f][t]*w[o][f].
template <int OUT, int FIN, int OPER, int FSPLIT>
__global__ void k_fc_a(const float* __restrict__ s, const float* __restrict__ wgt,
                       float* __restrict__ z) {
    constexpr int OG = OUT / OPER, FCH = FIN / FSPLIT;
    int idx = blockIdx.x * 256 + threadIdx.x;
    if (idx >= NBATCH * OG * TC * FSPLIT) return;
    int tc = idx % TC;
    int og = (idx / TC) % OG;
    int n  = (idx / (TC * OG)) % NBATCH;
    int sp = idx / (TC * OG * NBATCH);
    const float* sb = s + (size_t)n * FIN * TT + (size_t)sp * FCH * TT + tc * 4;
    const float* wb = wgt + (size_t)sp * FCH;
    float acc[OPER][4];
#pragma unroll
    for (int k = 0; k < OPER; ++k) { acc[k][0] = acc[k][1] = acc[k][2] = acc[k][3] = 0.f; }
#pragma unroll 2
    for (int f = 0; f < FCH; f += 4) {
        float4 s0 = *(const float4*)(sb + (size_t)(f + 0) * TT);
        float4 s1 = *(const float4*)(sb + (size_t)(f + 1) * TT);
        float4 s2 = *(const float4*)(sb + (size_t)(f + 2) * TT);
        float4 s3 = *(const float4*)(sb + (size_t)(f + 3) * TT);
#pragma unroll
        for (int k = 0; k < OPER; ++k) {
            float4 wv = *(const float4*)(wb + (size_t)(og * OPER + k) * FIN + f);
            acc[k][0] += wv.x * s0.x + wv.y * s1.x + wv.z * s2.x + wv.w * s3.x;
            acc[k][1] += wv.x * s0.y + wv.y * s1.y + wv.z * s2.y + wv.w * s3.y;
            acc[k][2] += wv.x * s0.z + wv.y * s1.z + wv.z * s2.z + wv.w * s3.z;
            acc[k][3] += wv.x * s0.w + wv.y * s1.w + wv.z * s2.w + wv.w * s3.w;
        }
    }
#pragma unroll
    for (int k = 0; k < OPER; ++k) {
        float4 o; o.x = acc[k][0]; o.y = acc[k][1]; o.z = acc[k][2]; o.w = acc[k][3];
        *(float4*)(z + ((size_t)sp * NBATCH * OUT + (size_t)n * OUT + og * OPER + k) * TT + tc * 4) = o;
    }
}

extern "C" void kernel_launch(void* const* d_in, const int* in_sizes, int n_in,
                              void* d_out, int out_size, void* d_ws, size_t ws_size,
                              hipStream_t stream) {
    const float* s_in = (const float*)d_in[0]; // (4,2,128,128,300)
    const float* w1   = (const float*)d_in[1]; // (32,2,5,5)
    const float* w2   = (const float*)d_in[2]; // (64,32,3,3)
    const float* w3   = (const float*)d_in[3]; // (64,64,3,3)
    const float* w4a  = (const float*)d_in[4]; // (256,4096)
    const float* w4b  = (const float*)d_in[5]; // (11,256)
    float* out = (float*)d_out;                // (4,11,300)

    // Workspace (floats): Z 39,321,600 (pre-activations/partials + reduced copies)
    // | Sb 9,830,400 (spike buffers, time-multiplexed) | packed weights. ~196.8 MB.
    float* Z  = (float*)d_ws;
    float* Sb = Z + 39321600;
    float* WP = Sb + 9830400;
    float* w1p = WP;           // 50*32   = 1600
    float* w2p = WP + 1600;    // 288*64  = 18432
    float* w3p = WP + 20032;   // 576*64  = 36864

    auto g = [](int n) { return (n + 255) / 256; };
    auto g64 = [](int n) { return (n + 63) / 64; };

    k_pack_w<<<g(1600),  256, 0, stream>>>(w1, w1p, 50, 32, 1600);
    k_pack_w<<<g(18432), 256, 0, stream>>>(w2, w2p, 288, 64, 18432);
    k_pack_w<<<g(36864), 256, 0, stream>>>(w3, w3p, 576, 64, 36864);

    // L0: 4x4 pool + psp -> s0 (4,2,32,32,300) @ Sb
    k_pool4<<<g(614400), 256, 0, stream>>>(s_in, Z);
    k_scan<<<g64(8192), 64, 0, stream>>>(Z, Sb, 8192);

    // L1 conv 5x5 (2->32, 32x32): z1 (39.3M) @ Z. 2400 blocks exact.
    k_conv_lds<1, 2, 32, 32, 32, 5, 2><<<2400, 256, 0, stream>>>(Sb, w1p, Z);
    // L1 psp + 2x2 pool + L2 psp -> s2 (4,32,16,16,300) @ Sb
    k_scan_pool_scan<1, 32, 16, 16><<<g(32768), 256, 0, stream>>>(Z, Sb, 0);

    // L3 conv 3x3 (32->64, 16x16), ci-split 2: z3 (2 x 19.66M) @ Z. 2400 blocks exact.
    k_conv_lds<2, 32, 64, 16, 16, 3, 1><<<2400, 256, 0, stream>>>(Sb, w2p, Z);
    // L3 psp + 2x2 pool + L4 psp -> s4 (4,64,8,8,300) @ Sb
    k_scan_pool_scan<2, 64, 8, 8><<<g(16384), 256, 0, stream>>>(Z, Sb, 19660800);

    // L5 conv 3x3 (64->64, 8x8), ci-split 4: z5 (4 x 4.92M) @ Z. 1200 blocks exact.
    k_conv_lds<4, 64, 64, 8, 8, 3, 1><<<1200, 256, 0, stream>>>(Sb, w3p, Z);
    // coalesced 4->1 reduce, then scan -> s5 @ Sb
    k_reduce<4><<<g(1228800), 256, 0, stream>>>(Z, Z + 19660800, 1228800, 4915200);
    k_scan<<<g64(16384), 64, 0, stream>>>(Z + 19660800, Sb, 16384);

    // L6: fc 4096->256, 16-way f-split: z6 (16 x 307200) @ Z. 600 blocks.
    k_fc_a<256, 4096, 8, 16><<<600, 256, 0, stream>>>(Sb, w4a, Z);
    k_reduce<16><<<g(76800), 256, 0, stream>>>(Z, Z + 4915200, 76800, 307200);
    k_scan<<<g64(1024), 64, 0, stream>>>(Z + 4915200, Sb, 1024);

    // L7: fc 256->11 + psp -> out
    k_fc_a<11, 256, 1, 1><<<g(3300), 256, 0, stream>>>(Sb, w4b, Z);
    k_scan<<<1, 64, 0, stream>>>(Z, out, 44);
}

// Round 5
// 884.162 us; speedup vs baseline: 5.2962x; 1.2497x over previous
//
#include <hip/hip_runtime.h>
#include <cstdint>

#define TT 300   // timesteps
#define TC 75    // TT/4
#define NBATCH 4

// PSP + refractory IIR step, exact op order of the reference scan.
__device__ __forceinline__ void psp_step(float z, float& gp, float& hp, float& gr, float& hr, float& s_out) {
    hp = 0.90483741803595957f * (hp + gp);      // a_sr = exp(-1/10)
    gp = 0.90483741803595957f * gp + z;
    hr = 0.36787944117144233f * (hr + gr);      // a_rf = exp(-1)
    gr = 0.36787944117144233f * gr;
    float u = 0.27182818284590452f * hp + (-54.365636569180904f) * hr; // c_sr*hp + c_rf*hr
    float s = (u >= 10.0f) ? 1.0f : 0.0f;
    gr += s;
    s_out = s;
}

// Coalesced R-way partial reduce: zr[p][t] = sum_r z[r*pstride + p*TT + t].
template <int R>
__global__ void k_reduce(const float* __restrict__ z, float* __restrict__ zr,
                         int total4, int pstride) {
    int i = blockIdx.x * 256 + threadIdx.x;
    if (i >= total4) return;
    size_t pos = (size_t)i * 4;
    float4 a = *(const float4*)(z + pos);
#pragma unroll
    for (int r = 1; r < R; ++r) {
        float4 b = *(const float4*)(z + (size_t)r * pstride + pos);
        a.x += b.x; a.y += b.y; a.z += b.z; a.w += b.w;
    }
    *(float4*)(zr + pos) = a;
}

// Per-neuron scan over T with fused R-way partial reduce, 12-step chunks:
// all R*3 float4 loads issued up front per chunk (deep MLP), then 12 IIR steps.
template <int R>
__global__ void k_scan_redp(const float* __restrict__ z, float* __restrict__ s,
                            int n_neur, int pstride) {
    int i = blockIdx.x * 64 + threadIdx.x;
    if (i >= n_neur) return;
    const float* zp = z + (size_t)i * TT;
    float* sp = s + (size_t)i * TT;
    float gp = 0.f, hp = 0.f, gr = 0.f, hr = 0.f;
#pragma unroll 1
    for (int c = 0; c < 25; ++c) {
        const float* p = zp + c * 12;
        float4 a0 = *(const float4*)(p);
        float4 a1 = *(const float4*)(p + 4);
        float4 a2 = *(const float4*)(p + 8);
#pragma unroll
        for (int r = 1; r < R; ++r) {
            const float* pr = p + (size_t)r * pstride;
            float4 b0 = *(const float4*)(pr);
            float4 b1 = *(const float4*)(pr + 4);
            float4 b2 = *(const float4*)(pr + 8);
            a0.x += b0.x; a0.y += b0.y; a0.z += b0.z; a0.w += b0.w;
            a1.x += b1.x; a1.y += b1.y; a1.z += b1.z; a1.w += b1.w;
            a2.x += b2.x; a2.y += b2.y; a2.z += b2.z; a2.w += b2.w;
        }
        float4 o0, o1, o2;
        psp_step(a0.x, gp, hp, gr, hr, o0.x);
        psp_step(a0.y, gp, hp, gr, hr, o0.y);
        psp_step(a0.z, gp, hp, gr, hr, o0.z);
        psp_step(a0.w, gp, hp, gr, hr, o0.w);
        psp_step(a1.x, gp, hp, gr, hr, o1.x);
        psp_step(a1.y, gp, hp, gr, hr, o1.y);
        psp_step(a1.z, gp, hp, gr, hr, o1.z);
        psp_step(a1.w, gp, hp, gr, hr, o1.w);
        psp_step(a2.x, gp, hp, gr, hr, o2.x);
        psp_step(a2.y, gp, hp, gr, hr, o2.y);
        psp_step(a2.z, gp, hp, gr, hr, o2.z);
        psp_step(a2.w, gp, hp, gr, hr, o2.w);
        float* q = sp + c * 12;
        *(float4*)(q) = o0;
        *(float4*)(q + 4) = o1;
        *(float4*)(q + 8) = o2;
    }
}

// Fused scan-pool-scan, thread per CONV neuron (4x parallelism vs pooled-neuron version).
// Thread i: quad position q=i&3 (dy=q>>1,dx=q&1), pooled neuron p=i>>2.
// Quad spike sum via shfl_xor(1),shfl_xor(2) — exact (spikes are 0/1 ints in fp32).
// Pooled IIR computed redundantly in all 4 lanes; lane q==0 writes.
// z layout: [r][n][C][H][W][T] (R partials, stride pstride), s out: [n][C][H2][W2][T].
template <int R, int C, int H2, int W2>
__global__ void __launch_bounds__(256) k_spsq(const float* __restrict__ z,
                                              float* __restrict__ s, int pstride) {
    constexpr int H = 2 * H2, W = 2 * W2;
    int i = blockIdx.x * 256 + threadIdx.x;   // grid exact: NBATCH*C*H*W threads
    int q  = i & 3;
    int p  = i >> 2;
    int x2 = p % W2;
    int y2 = (p / W2) % H2;
    int c  = (p / (W2 * H2)) % C;
    int n  = p / (W2 * H2 * C);
    int dy = q >> 1, dx = q & 1;
    const float* zp = z + (((size_t)(n * C + c) * H + 2 * y2 + dy) * W + 2 * x2 + dx) * TT;
    float* so = s + (size_t)p * TT;
    float gp = 0.f, hp = 0.f, gr = 0.f, hr = 0.f;   // conv neuron IIR
    float Gp = 0.f, Hp = 0.f, Gr = 0.f, Hr = 0.f;   // pooled neuron IIR
#pragma unroll 1
    for (int cc = 0; cc < 25; ++cc) {
        const float* pp = zp + cc * 12;
        float4 a0 = *(const float4*)(pp);
        float4 a1 = *(const float4*)(pp + 4);
        float4 a2 = *(const float4*)(pp + 8);
#pragma unroll
        for (int r = 1; r < R; ++r) {
            const float* pr = pp + (size_t)r * pstride;
            float4 b0 = *(const float4*)(pr);
            float4 b1 = *(const float4*)(pr + 4);
            float4 b2 = *(const float4*)(pr + 8);
            a0.x += b0.x; a0.y += b0.y; a0.z += b0.z; a0.w += b0.w;
            a1.x += b1.x; a1.y += b1.y; a1.z += b1.z; a1.w += b1.w;
            a2.x += b2.x; a2.y += b2.y; a2.z += b2.z; a2.w += b2.w;
        }
        float zv[12] = {a0.x, a0.y, a0.z, a0.w, a1.x, a1.y, a1.z, a1.w, a2.x, a2.y, a2.z, a2.w};
        float ov[12];
#pragma unroll
        for (int tt = 0; tt < 12; ++tt) {
            float sq;
            psp_step(zv[tt], gp, hp, gr, hr, sq);
            float t1 = sq + __shfl_xor(sq, 1, 64);
            float pool = t1 + __shfl_xor(t1, 2, 64);
            psp_step(11.0f * pool, Gp, Hp, Gr, Hr, ov[tt]);
        }
        if (q == 0) {
            float* qo = so + cc * 12;
            *(float4*)(qo)     = make_float4(ov[0], ov[1], ov[2],  ov[3]);
            *(float4*)(qo + 4) = make_float4(ov[4], ov[5], ov[6],  ov[7]);
            *(float4*)(qo + 8) = make_float4(ov[8], ov[9], ov[10], ov[11]);
        }
    }
}

// Transpose-pack OIHW weights (COUT, S) -> [s][COUT] so one tap's weights are contiguous.
__global__ void k_pack_w(const float* __restrict__ w, float* __restrict__ wp, int S, int CO, int total) {
    int i = blockIdx.x * 256 + threadIdx.x;
    if (i >= total) return;
    int co = i % CO, s = i / CO;
    wp[i] = w[co * S + s];
}

// 4x4 sum-pool * 11.0 over (N,2,128,128,T) -> z (N,2,32,32,T). Thread = (p, tc), tc fastest.
__global__ void k_pool4(const float* __restrict__ x, float* __restrict__ z) {
    int idx = blockIdx.x * 256 + threadIdx.x;
    if (idx >= NBATCH * 2 * 32 * 32 * TC) return;
    int tc = idx % TC;
    int p  = idx / TC;
    int w  = p % 32;
    int h  = (p / 32) % 32;
    int nc = p / (32 * 32);
    const float* base = x + (((size_t)nc * 128 + h * 4) * 128 + w * 4) * TT + tc * 4;
    float ax = 0.f, ay = 0.f, az = 0.f, aw = 0.f;
#pragma unroll
    for (int i = 0; i < 4; ++i)
#pragma unroll
        for (int j = 0; j < 4; ++j) {
            float4 v = *(const float4*)(base + ((size_t)i * 128 + j) * TT);
            ax += v.x; ay += v.y; az += v.z; aw += v.w;
        }
    float4 o; o.x = 11.0f * ax; o.y = 11.0f * ay; o.z = 11.0f * az; o.w = 11.0f * aw;
    *(float4*)(z + (size_t)p * TT + tc * 4) = o;
}

// LDS-weight conv. Thread = (sp, cb, n, y, x, tc): 16 output channels x 4 timesteps in regs.
// z out: [sp][n][COUT][H][W][T].
template <int SPLIT, int CIN, int COUT, int H, int W, int K, int PAD>
__global__ void __launch_bounds__(256) k_conv_lds(const float* __restrict__ s_in,
                                                  const float* __restrict__ wp,
                                                  float* __restrict__ z) {
    constexpr int CBN = COUT / 16;
    constexpr int CIN_SP = CIN / SPLIT;
    constexpr int S_SP = CIN_SP * K * K;
    __shared__ float wlds[S_SP * COUT];
    int sp = (int)(((size_t)blockIdx.x * 256) / (CBN * NBATCH * H * W * TC));
    {
        const float4* src = (const float4*)(wp + (size_t)sp * S_SP * COUT);
        float4* dst = (float4*)wlds;
        for (int i = threadIdx.x; i < S_SP * COUT / 4; i += 256) dst[i] = src[i];
    }
    __syncthreads();
    int t = blockIdx.x * 256 + threadIdx.x;
    int tc = t % TC; t /= TC;
    int x  = t % W;  t /= W;
    int y  = t % H;  t /= H;
    int n  = t % NBATCH; t /= NBATCH;
    int cb = t % CBN;
    const float* sb = s_in + ((size_t)n * CIN + sp * CIN_SP) * H * W * TT + tc * 4;
    float acc[4][4][4]; // [cg][c][t]
#pragma unroll
    for (int a = 0; a < 4; ++a)
#pragma unroll
        for (int b = 0; b < 4; ++b)
#pragma unroll
            for (int d = 0; d < 4; ++d) acc[a][b][d] = 0.f;
#pragma unroll 1
    for (int cl = 0; cl < CIN_SP; ++cl) {
#pragma unroll
        for (int ky = 0; ky < K; ++ky) {
            int yy = y + ky - PAD;
            if (yy < 0 || yy >= H) continue;
#pragma unroll
            for (int kx = 0; kx < K; ++kx) {
                int xx = x + kx - PAD;
                if (xx < 0 || xx >= W) continue;
                float4 v = *(const float4*)(sb + ((size_t)(cl * H + yy) * W + xx) * TT);
                float va[4] = {v.x, v.y, v.z, v.w};
                const float* wrow = &wlds[((cl * K + ky) * K + kx) * COUT + cb * 16];
#pragma unroll
                for (int cg = 0; cg < 4; ++cg) {
                    float4 wv = *(const float4*)(wrow + cg * 4);
                    float wa[4] = {wv.x, wv.y, wv.z, wv.w};
#pragma unroll
                    for (int c = 0; c < 4; ++c)
#pragma unroll
                        for (int tt = 0; tt < 4; ++tt)
                            acc[cg][c][tt] += wa[c] * va[tt];
                }
            }
        }
    }
    float* zb = z + (((size_t)(sp * NBATCH + n) * COUT + cb * 16) * H * W + (size_t)y * W + x) * TT + tc * 4;
#pragma unroll
    for (int cg = 0; cg < 4; ++cg)
#pragma unroll
        for (int c = 0; c < 4; ++c) {
            float4 o; o.x = acc[cg][c][0]; o.y = acc[cg][c][1]; o.z = acc[cg][c][2]; o.w = acc[cg][c][3];
            *(float4*)(zb + (size_t)(cg * 4 + c) * H * W * TT) = o;
        }
}

// FC with f-split: partial z[sp][n][o][t] = sum_{f in chunk sp} s[n][f][t]*w[o][f].
template <int OUT, int FIN, int OPER, int FSPLIT>
__global__ void k_fc_a(const float* __restrict__ s, const float* __restrict__ wgt,
                       float* __restrict__ z) {
    constexpr int OG = OUT / OPER, FCH = FIN / FSPLIT;
    int idx = blockIdx.x * 256 + threadIdx.x;
    if (idx >= NBATCH * OG * TC * FSPLIT) return;
    int tc = idx % TC;
    int og = (idx / TC) % OG;
    int n  = (idx / (TC * OG)) % NBATCH;
    int sp = idx / (TC * OG * NBATCH);
    const float* sb = s + (size_t)n * FIN * TT + (size_t)sp * FCH * TT + tc * 4;
    const float* wb = wgt + (size_t)sp * FCH;
    float acc[OPER][4];
#pragma unroll
    for (int k = 0; k < OPER; ++k) { acc[k][0] = acc[k][1] = acc[k][2] = acc[k][3] = 0.f; }
#pragma unroll 2
    for (int f = 0; f < FCH; f += 4) {
        float4 s0 = *(const float4*)(sb + (size_t)(f + 0) * TT);
        float4 s1 = *(const float4*)(sb + (size_t)(f + 1) * TT);
        float4 s2 = *(const float4*)(sb + (size_t)(f + 2) * TT);
        float4 s3 = *(const float4*)(sb + (size_t)(f + 3) * TT);
#pragma unroll
        for (int k = 0; k < OPER; ++k) {
            float4 wv = *(const float4*)(wb + (size_t)(og * OPER + k) * FIN + f);
            acc[k][0] += wv.x * s0.x + wv.y * s1.x + wv.z * s2.x + wv.w * s3.x;
            acc[k][1] += wv.x * s0.y + wv.y * s1.y + wv.z * s2.y + wv.w * s3.y;
            acc[k][2] += wv.x * s0.z + wv.y * s1.z + wv.z * s2.z + wv.w * s3.z;
            acc[k][3] += wv.x * s0.w + wv.y * s1.w + wv.z * s2.w + wv.w * s3.w;
        }
    }
#pragma unroll
    for (int k = 0; k < OPER; ++k) {
        float4 o; o.x = acc[k][0]; o.y = acc[k][1]; o.z = acc[k][2]; o.w = acc[k][3];
        *(float4*)(z + ((size_t)sp * NBATCH * OUT + (size_t)n * OUT + og * OPER + k) * TT + tc * 4) = o;
    }
}

extern "C" void kernel_launch(void* const* d_in, const int* in_sizes, int n_in,
                              void* d_out, int out_size, void* d_ws, size_t ws_size,
                              hipStream_t stream) {
    const float* s_in = (const float*)d_in[0]; // (4,2,128,128,300)
    const float* w1   = (const float*)d_in[1]; // (32,2,5,5)
    const float* w2   = (const float*)d_in[2]; // (64,32,3,3)
    const float* w3   = (const float*)d_in[3]; // (64,64,3,3)
    const float* w4a  = (const float*)d_in[4]; // (256,4096)
    const float* w4b  = (const float*)d_in[5]; // (11,256)
    float* out = (float*)d_out;                // (4,11,300)

    // Workspace (floats): Z 39,321,600 | Sb 9,830,400 (time-multiplexed spikes) | packed w.
    float* Z  = (float*)d_ws;
    float* Sb = Z + 39321600;
    float* WP = Sb + 9830400;
    float* w1p = WP;           // 50*32   = 1600
    float* w2p = WP + 1600;    // 288*64  = 18432
    float* w3p = WP + 20032;   // 576*64  = 36864

    auto g = [](int n) { return (n + 255) / 256; };
    auto g64 = [](int n) { return (n + 63) / 64; };

    k_pack_w<<<g(1600),  256, 0, stream>>>(w1, w1p, 50, 32, 1600);
    k_pack_w<<<g(18432), 256, 0, stream>>>(w2, w2p, 288, 64, 18432);
    k_pack_w<<<g(36864), 256, 0, stream>>>(w3, w3p, 576, 64, 36864);

    // L0: 4x4 pool + psp -> s0 (4,2,32,32,300) @ Sb
    k_pool4<<<g(614400), 256, 0, stream>>>(s_in, Z);
    k_scan_redp<1><<<g64(8192), 64, 0, stream>>>(Z, Sb, 8192, 0);

    // L1 conv 5x5 (2->32, 32x32): z1 (39.3M) @ Z. 2400 blocks exact.
    k_conv_lds<1, 2, 32, 32, 32, 5, 2><<<2400, 256, 0, stream>>>(Sb, w1p, Z);
    // L1 psp + 2x2 pool + L2 psp -> s2 (4,32,16,16,300) @ Sb. 131072 threads = 512 blocks.
    k_spsq<1, 32, 16, 16><<<512, 256, 0, stream>>>(Z, Sb, 0);

    // L3 conv 3x3 (32->64, 16x16), ci-split 2: z3 (2 x 19.66M) @ Z. 2400 blocks exact.
    k_conv_lds<2, 32, 64, 16, 16, 3, 1><<<2400, 256, 0, stream>>>(Sb, w2p, Z);
    // L3 psp + 2x2 pool + L4 psp -> s4 (4,64,8,8,300) @ Sb. 65536 threads = 256 blocks.
    k_spsq<2, 64, 8, 8><<<256, 256, 0, stream>>>(Z, Sb, 19660800);

    // L5 conv 3x3 (64->64, 8x8), ci-split 4: z5 (4 x 4.92M) @ Z. 1200 blocks exact.
    k_conv_lds<4, 64, 64, 8, 8, 3, 1><<<1200, 256, 0, stream>>>(Sb, w3p, Z);
    // fused 4-way reduce + scan -> s5 @ Sb (16384 neurons, 256 blocks of 64)
    k_scan_redp<4><<<g64(16384), 64, 0, stream>>>(Z, Sb, 16384, 4915200);

    // L6: fc 4096->256, 16-way f-split: z6 (16 x 307200) @ Z. 600 blocks.
    k_fc_a<256, 4096, 8, 16><<<600, 256, 0, stream>>>(Sb, w4a, Z);
    k_reduce<16><<<g(76800), 256, 0, stream>>>(Z, Z + 4915200, 76800, 307200);
    k_scan_redp<1><<<g64(1024), 64, 0, stream>>>(Z + 4915200, Sb, 1024, 0);

    // L7: fc 256->11 + psp -> out
    k_fc_a<11, 256, 1, 1><<<g(3300), 256, 0, stream>>>(Sb, w4b, Z);
    k_scan_redp<1><<<1, 64, 0, stream>>>(Z, out, 44, 0);
}